// Round 1
// baseline (90.138 us; speedup 1.0000x reference)
//
#include <hip/hip_runtime.h>

typedef unsigned short u16;
typedef __attribute__((ext_vector_type(8))) short bf16x8;  // 8 bf16 = 4 VGPRs (MFMA A/B frag)
typedef __attribute__((ext_vector_type(4))) float f32x4;   // MFMA C/D frag

constexpr int   kN    = 8192;
constexpr int   kD    = 256;
constexpr float kInvD = 1.0f / 256.0f;
constexpr float kInv2D = 2.0f / 256.0f;   // 2/D
constexpr float kInvN = 1.0f / 8192.0f;
constexpr int   kMaxB = 128;              // max rows per id bucket (P(>128) ~ 0)

#define GLOAD_LDS16(gptr, ldsptr)                                                   \
  __builtin_amdgcn_global_load_lds(                                                 \
      (const __attribute__((address_space(1))) unsigned int*)(gptr),                \
      (__attribute__((address_space(3))) unsigned int*)(ldsptr), 16, 0, 0)

// ---------------------------------------------------------------------------
// Kernel 1: prep — f32 -> bf16 convert, row sum-of-squares, id bucketing.
// One wave per row (4 rows / 256-thread block).
// ---------------------------------------------------------------------------
__global__ __launch_bounds__(256) void prep_kernel(
    const float* __restrict__ samples, const float* __restrict__ input1,
    u16* __restrict__ bf, float* __restrict__ sq,
    int* __restrict__ bcount, int* __restrict__ brows)
{
  const int row  = blockIdx.x * 4 + (threadIdx.x >> 6);
  const int lane = threadIdx.x & 63;

  const float4 v = *(const float4*)(samples + (size_t)row * kD + lane * 4);

  // bf16 convert, round-to-nearest-even
  float tmp[4] = {v.x, v.y, v.z, v.w};
  u16 h[4];
#pragma unroll
  for (int i = 0; i < 4; ++i) {
    union { float f; unsigned u; } c;
    c.f = tmp[i];
    unsigned r = c.u + 0x7fffu + ((c.u >> 16) & 1u);
    h[i] = (u16)(r >> 16);
  }
  *(ushort4*)(bf + (size_t)row * kD + lane * 4) = make_ushort4(h[0], h[1], h[2], h[3]);

  float ss = v.x * v.x + v.y * v.y + v.z * v.z + v.w * v.w;
#pragma unroll
  for (int m = 32; m >= 1; m >>= 1) ss += __shfl_xor(ss, m);

  if (lane == 0) {
    sq[row] = ss;
    // ids[i] = input1[i, 0, F-1] -> flat index row*T*F + 7
    int id  = (int)input1[row * 32 + 7];
    int pos = atomicAdd(&bcount[id], 1);
    if (pos < kMaxB) brows[id * kMaxB + pos] = row;
  }
}

// ---------------------------------------------------------------------------
// Kernel 2: dense pass — per i-row accumulate sum_j (S_ij - 1)^2.
// BM=BN=128, BK=64 LDS tiles; 4 waves 2x2; mfma_f32_16x16x32_bf16 4x4/wave.
// global_load_lds (16B) staging, XOR-swizzled source + swizzled ds_read_b128
// (rule #21: linear LDS dest, same involution on source and read).
// Grid: (N/128) x 8 j-chunks; each block walks 8 j-tiles of 128.
// ---------------------------------------------------------------------------
__global__ __launch_bounds__(256, 2) void simloss_main(
    const u16* __restrict__ bf, const float* __restrict__ sq,
    float* __restrict__ out)
{
  __shared__ u16 Abuf[128 * 64];  // 16 KB
  __shared__ u16 Bbuf[128 * 64];  // 16 KB

  const int tid  = threadIdx.x;
  const int lane = tid & 63;
  const int w    = tid >> 6;       // wave 0..3
  const int wm   = w >> 1;         // wave row (0..1)
  const int wn   = w & 1;          // wave col (0..1)
  const int llo  = lane & 15;
  const int lhi  = lane >> 4;

  const int i0    = blockIdx.x * 128;
  const int jbase = blockIdx.y * 1024;

  // hoisted per-lane row data: sq_i/D for the 16 output rows this lane owns
  float sqi_s[4][4];
#pragma unroll
  for (int mi = 0; mi < 4; ++mi)
#pragma unroll
    for (int r = 0; r < 4; ++r)
      sqi_s[mi][r] = sq[i0 + wm * 64 + mi * 16 + lhi * 4 + r] * kInvD;

  float rowacc[4][4] = {};  // per-lane partial sum_j (S-1)^2 for 16 rows

  const int sr = tid >> 3;  // staging row within 32-row chunk
  const int sl = tid & 7;   // staging 16B slot within 128B row

  for (int jt = 0; jt < 8; ++jt) {
    const int j0 = jbase + jt * 128;

    f32x4 zero4 = {0.f, 0.f, 0.f, 0.f};
    f32x4 acc[4][4];
#pragma unroll
    for (int mi = 0; mi < 4; ++mi)
#pragma unroll
      for (int ni = 0; ni < 4; ++ni) acc[mi][ni] = zero4;

#pragma unroll
    for (int kt = 0; kt < 4; ++kt) {
      const int k0 = kt * 64;
      // stage A[128x64] and B[128x64] bf16 tiles: 4 calls x 16B/thread each
#pragma unroll
      for (int c = 0; c < 4; ++c) {
        const int r   = c * 32 + sr;
        const int ksl = sl ^ (r & 7);  // inverse-swizzled global source
        const u16* ga = bf + (size_t)(i0 + r) * kD + k0 + ksl * 8;
        const u16* gb = bf + (size_t)(j0 + r) * kD + k0 + ksl * 8;
        GLOAD_LDS16(ga, Abuf + r * 64 + sl * 8);  // linear dest = tid*16B
        GLOAD_LDS16(gb, Bbuf + r * 64 + sl * 8);
      }
      __syncthreads();

#pragma unroll
      for (int k32 = 0; k32 < 2; ++k32) {
        bf16x8 a[4], b[4];
#pragma unroll
        for (int mi = 0; mi < 4; ++mi) {
          const int ra   = wm * 64 + mi * 16 + llo;
          const int slot = (k32 * 4 + lhi) ^ (ra & 7);  // swizzled read
          a[mi] = *(const bf16x8*)(Abuf + ra * 64 + slot * 8);
        }
#pragma unroll
        for (int ni = 0; ni < 4; ++ni) {
          const int rb   = wn * 64 + ni * 16 + llo;
          const int slot = (k32 * 4 + lhi) ^ (rb & 7);
          b[ni] = *(const bf16x8*)(Bbuf + rb * 64 + slot * 8);
        }
#pragma unroll
        for (int mi = 0; mi < 4; ++mi)
#pragma unroll
          for (int ni = 0; ni < 4; ++ni)
            acc[mi][ni] = __builtin_amdgcn_mfma_f32_16x16x32_bf16(
                a[mi], b[ni], acc[mi][ni], 0, 0, 0);
      }
      __syncthreads();
    }

    // epilogue: rowacc += (S-1)^2, 3 VALU ops per element
    float sqjm1[4];
#pragma unroll
    for (int ni = 0; ni < 4; ++ni)
      sqjm1[ni] = sq[j0 + wn * 64 + ni * 16 + llo] * kInvD - 1.0f;

#pragma unroll
    for (int mi = 0; mi < 4; ++mi)
#pragma unroll
      for (int ni = 0; ni < 4; ++ni)
#pragma unroll
        for (int r = 0; r < 4; ++r) {
          // S-1 = (sq_i + sq_j)/D - 1 - (2/D)*gram
          float s1 = fmaf(acc[mi][ni][r], -kInv2D, sqi_s[mi][r] + sqjm1[ni]);
          rowacc[mi][r] = fmaf(s1, s1, rowacc[mi][r]);
        }
  }

  // reduce partial row sums across the 16 lanes of each lhi group, then atomic
#pragma unroll
  for (int mi = 0; mi < 4; ++mi)
#pragma unroll
    for (int r = 0; r < 4; ++r) {
      float v = rowacc[mi][r];
      v += __shfl_xor(v, 1);
      v += __shfl_xor(v, 2);
      v += __shfl_xor(v, 4);
      v += __shfl_xor(v, 8);
      if (llo == 0)
        atomicAdd(&out[i0 + wm * 64 + mi * 16 + lhi * 4 + r], v * kInvN);
    }
}

// ---------------------------------------------------------------------------
// Kernel 3: sparse correction — for id-matching pairs (incl. diagonal) add
// eq*(2*S_ij - 1)/N with exact f32 dot. ~73k pairs total.
// One 64-thread block per id bucket.
// ---------------------------------------------------------------------------
__global__ __launch_bounds__(64) void corr_kernel(
    const float* __restrict__ samples, const float* __restrict__ sq,
    const int* __restrict__ bcount, const int* __restrict__ brows,
    float* __restrict__ out)
{
  const int b = blockIdx.x;
  int cnt = bcount[b];
  if (cnt <= 0) return;
  if (cnt > kMaxB) cnt = kMaxB;
  const int tot = cnt * cnt;

  for (int p = threadIdx.x; p < tot; p += 64) {
    const int ia = brows[b * kMaxB + p / cnt];
    const int jb = brows[b * kMaxB + p % cnt];
    const float4* xa = (const float4*)(samples + (size_t)ia * kD);
    const float4* xb = (const float4*)(samples + (size_t)jb * kD);
    float dot = 0.f;
#pragma unroll 8
    for (int k = 0; k < kD / 4; ++k) {
      const float4 va = xa[k], vb = xb[k];
      dot += va.x * vb.x + va.y * vb.y + va.z * vb.z + va.w * vb.w;
    }
    const float s = (sq[ia] + sq[jb] - 2.f * dot) * kInvD;
    atomicAdd(&out[ia], (2.f * s - 1.f) * kInvN);
  }
}

// ---------------------------------------------------------------------------
extern "C" void kernel_launch(void* const* d_in, const int* in_sizes, int n_in,
                              void* d_out, int out_size, void* d_ws, size_t ws_size,
                              hipStream_t stream) {
  const float* samples = (const float*)d_in[0];
  const float* input1  = (const float*)d_in[1];
  float* out = (float*)d_out;

  char* ws = (char*)d_ws;
  u16*   bf     = (u16*)ws;                                   // 4 MB bf16 samples
  float* sq     = (float*)(ws + (size_t)4 * 1024 * 1024);     // 32 KB
  int*   bcount = (int*)(ws + (size_t)4 * 1024 * 1024 + 32 * 1024);   // 4 KB
  int*   brows  = (int*)(ws + (size_t)4 * 1024 * 1024 + 36 * 1024);   // 512 KB

  hipMemsetAsync(out, 0, kN * sizeof(float), stream);
  hipMemsetAsync(bcount, 0, 1024 * sizeof(int), stream);

  prep_kernel<<<kN / 4, 256, 0, stream>>>(samples, input1, bf, sq, bcount, brows);
  simloss_main<<<dim3(kN / 128, 8), 256, 0, stream>>>(bf, sq, out);
  corr_kernel<<<1024, 64, 0, stream>>>(samples, sq, bcount, brows, out);
}

// Round 2
// 79.362 us; speedup vs baseline: 1.1358x; 1.1358x over previous
//
#include <hip/hip_runtime.h>

typedef unsigned short u16;
typedef __attribute__((ext_vector_type(8))) short bf16x8;  // 8 bf16 = 4 VGPRs (MFMA A/B frag)
typedef __attribute__((ext_vector_type(4))) float f32x4;   // MFMA C/D frag

constexpr int   kN    = 8192;
constexpr int   kD    = 256;
constexpr float kInvD = 1.0f / 256.0f;
constexpr float kInv2D = 2.0f / 256.0f;   // 2/D
constexpr float kInvN = 1.0f / 8192.0f;
constexpr int   kMaxB = 128;              // max rows per id bucket (P(>128) ~ 0)

#define GLOAD_LDS16(gptr, ldsptr)                                                   \
  __builtin_amdgcn_global_load_lds(                                                 \
      (const __attribute__((address_space(1))) unsigned int*)(gptr),                \
      (__attribute__((address_space(3))) unsigned int*)(ldsptr), 16, 0, 0)

// ---------------------------------------------------------------------------
// Kernel 1: prep — f32 -> bf16 convert, row sum-of-squares, id bucketing,
// and zeroing of out (replaces one memset node).
// One wave per row (4 rows / 256-thread block).
// ---------------------------------------------------------------------------
__global__ __launch_bounds__(256) void prep_kernel(
    const float* __restrict__ samples, const float* __restrict__ input1,
    u16* __restrict__ bf, float* __restrict__ sq,
    int* __restrict__ bcount, int* __restrict__ brows, float* __restrict__ out)
{
  const int row  = blockIdx.x * 4 + (threadIdx.x >> 6);
  const int lane = threadIdx.x & 63;

  const float4 v = *(const float4*)(samples + (size_t)row * kD + lane * 4);

  // bf16 convert, round-to-nearest-even
  float tmp[4] = {v.x, v.y, v.z, v.w};
  u16 h[4];
#pragma unroll
  for (int i = 0; i < 4; ++i) {
    union { float f; unsigned u; } c;
    c.f = tmp[i];
    unsigned r = c.u + 0x7fffu + ((c.u >> 16) & 1u);
    h[i] = (u16)(r >> 16);
  }
  *(ushort4*)(bf + (size_t)row * kD + lane * 4) = make_ushort4(h[0], h[1], h[2], h[3]);

  float ss = v.x * v.x + v.y * v.y + v.z * v.z + v.w * v.w;
#pragma unroll
  for (int m = 32; m >= 1; m >>= 1) ss += __shfl_xor(ss, m);

  if (lane == 0) {
    sq[row] = ss;
    out[row] = 0.0f;
    // ids[i] = input1[i, 0, F-1] -> flat index row*T*F + 7
    int id  = (int)input1[row * 32 + 7];
    int pos = atomicAdd(&bcount[id], 1);
    if (pos < kMaxB) brows[id * kMaxB + pos] = row;
  }
}

// ---------------------------------------------------------------------------
// Kernel 2: dense pass over the UPPER TRIANGLE of 128x128 tiles only.
// S is symmetric: off-diagonal tile (I,J), I<J, contributes (S-1)^2 to both
// row sums (out[i], i in I) and col sums (out[j], j in J); diagonal tiles to
// row sums only. 2080 blocks, one tile each; BK=64; 4 waves 2x2;
// mfma_f32_16x16x32_bf16 4x4/wave. global_load_lds (16B) staging with
// XOR-swizzled source + swizzled ds_read_b128 (rule #21).
// ---------------------------------------------------------------------------
__global__ __launch_bounds__(256, 3) void simloss_main(
    const u16* __restrict__ bf, const float* __restrict__ sq,
    float* __restrict__ out)
{
  __shared__ u16 Abuf[128 * 64];  // 16 KB
  __shared__ u16 Bbuf[128 * 64];  // 16 KB

  const int tid  = threadIdx.x;
  const int lane = tid & 63;
  const int w    = tid >> 6;       // wave 0..3
  const int wm   = w >> 1;         // wave row (0..1)
  const int wn   = w & 1;          // wave col (0..1)
  const int llo  = lane & 15;
  const int lhi  = lane >> 4;

  // decode linear block id -> triangle tile (tj <= ti): rows I=tj, cols J=ti
  const int b = blockIdx.x;
  int ti = (int)((sqrtf(8.0f * (float)b + 1.0f) - 1.0f) * 0.5f);
  while ((ti + 1) * (ti + 2) / 2 <= b) ++ti;
  while (ti * (ti + 1) / 2 > b) --ti;
  const int tj = b - ti * (ti + 1) / 2;
  const int i0 = tj * 128;
  const int j0 = ti * 128;
  const bool diag = (ti == tj);

  // per-lane row data: sq_i/D for the 16 output rows this lane owns
  float sqi_s[4][4];
#pragma unroll
  for (int mi = 0; mi < 4; ++mi)
#pragma unroll
    for (int r = 0; r < 4; ++r)
      sqi_s[mi][r] = sq[i0 + wm * 64 + mi * 16 + lhi * 4 + r] * kInvD;

  float sqjm1[4];
#pragma unroll
  for (int ni = 0; ni < 4; ++ni)
    sqjm1[ni] = sq[j0 + wn * 64 + ni * 16 + llo] * kInvD - 1.0f;

  const int sr = tid >> 3;  // staging row within 32-row chunk
  const int sl = tid & 7;   // staging 16B slot within 128B row

  f32x4 zero4 = {0.f, 0.f, 0.f, 0.f};
  f32x4 acc[4][4];
#pragma unroll
  for (int mi = 0; mi < 4; ++mi)
#pragma unroll
    for (int ni = 0; ni < 4; ++ni) acc[mi][ni] = zero4;

#pragma unroll
  for (int kt = 0; kt < 4; ++kt) {
    const int k0 = kt * 64;
    // stage A[128x64] and B[128x64] bf16 tiles: 4 calls x 16B/thread each
#pragma unroll
    for (int c = 0; c < 4; ++c) {
      const int r   = c * 32 + sr;
      const int ksl = sl ^ (r & 7);  // inverse-swizzled global source
      const u16* ga = bf + (size_t)(i0 + r) * kD + k0 + ksl * 8;
      const u16* gb = bf + (size_t)(j0 + r) * kD + k0 + ksl * 8;
      GLOAD_LDS16(ga, Abuf + r * 64 + sl * 8);  // linear dest = tid*16B
      GLOAD_LDS16(gb, Bbuf + r * 64 + sl * 8);
    }
    __syncthreads();

#pragma unroll
    for (int k32 = 0; k32 < 2; ++k32) {
      bf16x8 a[4], bb[4];
#pragma unroll
      for (int mi = 0; mi < 4; ++mi) {
        const int ra   = wm * 64 + mi * 16 + llo;
        const int slot = (k32 * 4 + lhi) ^ (ra & 7);  // swizzled read
        a[mi] = *(const bf16x8*)(Abuf + ra * 64 + slot * 8);
      }
#pragma unroll
      for (int ni = 0; ni < 4; ++ni) {
        const int rb   = wn * 64 + ni * 16 + llo;
        const int slot = (k32 * 4 + lhi) ^ (rb & 7);
        bb[ni] = *(const bf16x8*)(Bbuf + rb * 64 + slot * 8);
      }
#pragma unroll
      for (int mi = 0; mi < 4; ++mi)
#pragma unroll
        for (int ni = 0; ni < 4; ++ni)
          acc[mi][ni] = __builtin_amdgcn_mfma_f32_16x16x32_bf16(
              a[mi], bb[ni], acc[mi][ni], 0, 0, 0);
    }
    __syncthreads();
  }

  // epilogue: t = (S-1)^2 -> row sums always, col sums for off-diagonal tiles
  float rowacc[4][4] = {};
  float colacc[4] = {};
#pragma unroll
  for (int mi = 0; mi < 4; ++mi)
#pragma unroll
    for (int ni = 0; ni < 4; ++ni)
#pragma unroll
      for (int r = 0; r < 4; ++r) {
        // S-1 = (sq_i + sq_j)/D - 1 - (2/D)*gram
        float s1 = fmaf(acc[mi][ni][r], -kInv2D, sqi_s[mi][r] + sqjm1[ni]);
        float t  = s1 * s1;
        rowacc[mi][r] += t;
        colacc[ni] += t;
      }

  // row sums: reduce across the 16 llo lanes, atomic at llo==0
#pragma unroll
  for (int mi = 0; mi < 4; ++mi)
#pragma unroll
    for (int r = 0; r < 4; ++r) {
      float v = rowacc[mi][r];
      v += __shfl_xor(v, 1);
      v += __shfl_xor(v, 2);
      v += __shfl_xor(v, 4);
      v += __shfl_xor(v, 8);
      if (llo == 0)
        atomicAdd(&out[i0 + wm * 64 + mi * 16 + lhi * 4 + r], v * kInvN);
    }

  // col sums (off-diagonal tiles only): reduce across the 4 lhi groups
  if (!diag) {
#pragma unroll
    for (int ni = 0; ni < 4; ++ni) {
      float v = colacc[ni];
      v += __shfl_xor(v, 16);
      v += __shfl_xor(v, 32);
      if (lhi == 0)
        atomicAdd(&out[j0 + wn * 64 + ni * 16 + llo], v * kInvN);
    }
  }
}

// ---------------------------------------------------------------------------
// Kernel 3: sparse correction — for id-matching pairs (incl. diagonal) add
// eq*(2*S_ij - 1)/N with exact f32 dot. ~73k pairs total.
// 256 threads/block; each pair handled by a 16-lane group (lane-parallel dot).
// ---------------------------------------------------------------------------
__global__ __launch_bounds__(256) void corr_kernel(
    const float* __restrict__ samples, const float* __restrict__ sq,
    const int* __restrict__ bcount, const int* __restrict__ brows,
    float* __restrict__ out)
{
  const int b = blockIdx.x;
  int cnt = bcount[b];
  if (cnt <= 0) return;
  if (cnt > kMaxB) cnt = kMaxB;
  const int tot = cnt * cnt;

  const int g  = threadIdx.x >> 4;   // pair-group 0..15
  const int gl = threadIdx.x & 15;   // lane within group

  for (int p = g; p < tot; p += 16) {
    const int ia = brows[b * kMaxB + p / cnt];
    const int jb = brows[b * kMaxB + p % cnt];
    const float4* xa = (const float4*)(samples + (size_t)ia * kD) + gl * 4;
    const float4* xb = (const float4*)(samples + (size_t)jb * kD) + gl * 4;
    float dot = 0.f;
#pragma unroll
    for (int k = 0; k < 4; ++k) {
      const float4 va = xa[k], vb = xb[k];
      dot += va.x * vb.x + va.y * vb.y + va.z * vb.z + va.w * vb.w;
    }
    dot += __shfl_xor(dot, 1);
    dot += __shfl_xor(dot, 2);
    dot += __shfl_xor(dot, 4);
    dot += __shfl_xor(dot, 8);
    if (gl == 0) {
      const float s = (sq[ia] + sq[jb] - 2.f * dot) * kInvD;
      atomicAdd(&out[ia], (2.f * s - 1.f) * kInvN);
    }
  }
}

// ---------------------------------------------------------------------------
extern "C" void kernel_launch(void* const* d_in, const int* in_sizes, int n_in,
                              void* d_out, int out_size, void* d_ws, size_t ws_size,
                              hipStream_t stream) {
  const float* samples = (const float*)d_in[0];
  const float* input1  = (const float*)d_in[1];
  float* out = (float*)d_out;

  char* ws = (char*)d_ws;
  u16*   bf     = (u16*)ws;                                   // 4 MB bf16 samples
  float* sq     = (float*)(ws + (size_t)4 * 1024 * 1024);     // 32 KB
  int*   bcount = (int*)(ws + (size_t)4 * 1024 * 1024 + 32 * 1024);   // 4 KB
  int*   brows  = (int*)(ws + (size_t)4 * 1024 * 1024 + 36 * 1024);   // 512 KB

  hipMemsetAsync(bcount, 0, 1024 * sizeof(int), stream);

  prep_kernel<<<kN / 4, 256, 0, stream>>>(samples, input1, bf, sq, bcount, brows, out);
  simloss_main<<<64 * 65 / 2, 256, 0, stream>>>(bf, sq, out);
  corr_kernel<<<1024, 256, 0, stream>>>(samples, sq, bcount, brows, out);
}

// Round 3
// 70.771 us; speedup vs baseline: 1.2737x; 1.1214x over previous
//
#include <hip/hip_runtime.h>

typedef unsigned short u16;
typedef __attribute__((ext_vector_type(8))) short bf16x8;  // 8 bf16 = 4 VGPRs (MFMA A/B frag)
typedef __attribute__((ext_vector_type(4))) float f32x4;   // MFMA C/D frag

constexpr int   kN    = 8192;
constexpr int   kD    = 256;
constexpr float kInvD = 1.0f / 256.0f;
constexpr float kInv2D = 2.0f / 256.0f;   // 2/D
constexpr float kInvN = 1.0f / 8192.0f;

#define GLOAD_LDS16(gptr, ldsptr)                                                   \
  __builtin_amdgcn_global_load_lds(                                                 \
      (const __attribute__((address_space(1))) unsigned int*)(gptr),                \
      (__attribute__((address_space(3))) unsigned int*)(ldsptr), 16, 0, 0)

// ---------------------------------------------------------------------------
// Kernel 1: prep — f32 -> bf16 convert, packed {sum-of-squares, id} per row,
// zero out. One wave per row (4 rows / 256-thread block).
// ---------------------------------------------------------------------------
__global__ __launch_bounds__(256) void prep_kernel(
    const float* __restrict__ samples, const float* __restrict__ input1,
    u16* __restrict__ bf, float2* __restrict__ sqid, float* __restrict__ out)
{
  const int row  = blockIdx.x * 4 + (threadIdx.x >> 6);
  const int lane = threadIdx.x & 63;

  const float4 v = *(const float4*)(samples + (size_t)row * kD + lane * 4);

  // bf16 convert, round-to-nearest-even
  float tmp[4] = {v.x, v.y, v.z, v.w};
  u16 h[4];
#pragma unroll
  for (int i = 0; i < 4; ++i) {
    union { float f; unsigned u; } c;
    c.f = tmp[i];
    unsigned r = c.u + 0x7fffu + ((c.u >> 16) & 1u);
    h[i] = (u16)(r >> 16);
  }
  *(ushort4*)(bf + (size_t)row * kD + lane * 4) = make_ushort4(h[0], h[1], h[2], h[3]);

  float ss = v.x * v.x + v.y * v.y + v.z * v.z + v.w * v.w;
#pragma unroll
  for (int m = 32; m >= 1; m >>= 1) ss += __shfl_xor(ss, m);

  if (lane == 0) {
    // ids[i] = input1[i, 0, F-1] -> flat index row*T*F + 7 (float-exact int)
    sqid[row] = make_float2(ss, input1[row * 32 + 7]);
    out[row]  = 0.0f;
  }
}

// ---------------------------------------------------------------------------
// Kernel 2: dense pass over the UPPER TRIANGLE of 128x128 tiles.
// t_ij = (S_ij - 1 + eq_ij)^2 == (S_ij - objid_dist)^2 folded inline via
// float-exact id compare. Off-diagonal tile (I,J): t feeds row sums (out[i])
// AND col sums (out[j]); diagonal tiles feed row sums only. 2080 blocks;
// BK=64; 4 waves 2x2; mfma_f32_16x16x32_bf16 4x4/wave. global_load_lds (16B)
// staging with XOR-swizzled source + swizzled ds_read_b128 (rule #21).
// ---------------------------------------------------------------------------
__global__ __launch_bounds__(256, 4) void simloss_main(
    const u16* __restrict__ bf, const float2* __restrict__ sqid,
    float* __restrict__ out)
{
  __shared__ u16 Abuf[128 * 64];  // 16 KB
  __shared__ u16 Bbuf[128 * 64];  // 16 KB

  const int tid  = threadIdx.x;
  const int lane = tid & 63;
  const int w    = tid >> 6;       // wave 0..3
  const int wm   = w >> 1;         // wave row (0..1)
  const int wn   = w & 1;          // wave col (0..1)
  const int llo  = lane & 15;
  const int lhi  = lane >> 4;

  // decode linear block id -> triangle tile (tj <= ti): rows I=tj, cols J=ti
  const int b = blockIdx.x;
  int ti = (int)((sqrtf(8.0f * (float)b + 1.0f) - 1.0f) * 0.5f);
  while ((ti + 1) * (ti + 2) / 2 <= b) ++ti;
  while (ti * (ti + 1) / 2 > b) --ti;
  const int tj = b - ti * (ti + 1) / 2;
  const int i0 = tj * 128;
  const int j0 = ti * 128;
  const bool diag = (ti == tj);

  // per-lane row data: {sq_i/D, id_i} for the 16 output rows this lane owns
  float sqi_s[4][4], idi[4][4];
#pragma unroll
  for (int mi = 0; mi < 4; ++mi)
#pragma unroll
    for (int r = 0; r < 4; ++r) {
      const float2 p = sqid[i0 + wm * 64 + mi * 16 + lhi * 4 + r];
      sqi_s[mi][r] = p.x * kInvD;
      idi[mi][r]   = p.y;
    }

  float sqjm1[4], idj[4];
#pragma unroll
  for (int ni = 0; ni < 4; ++ni) {
    const float2 p = sqid[j0 + wn * 64 + ni * 16 + llo];
    sqjm1[ni] = p.x * kInvD - 1.0f;
    idj[ni]   = p.y;
  }

  const int sr = tid >> 3;  // staging row within 32-row chunk
  const int sl = tid & 7;   // staging 16B slot within 128B row

  f32x4 zero4 = {0.f, 0.f, 0.f, 0.f};
  f32x4 acc[4][4];
#pragma unroll
  for (int mi = 0; mi < 4; ++mi)
#pragma unroll
    for (int ni = 0; ni < 4; ++ni) acc[mi][ni] = zero4;

#pragma unroll
  for (int kt = 0; kt < 4; ++kt) {
    const int k0 = kt * 64;
    // stage A[128x64] and B[128x64] bf16 tiles: 4 calls x 16B/thread each
#pragma unroll
    for (int c = 0; c < 4; ++c) {
      const int r   = c * 32 + sr;
      const int ksl = sl ^ (r & 7);  // inverse-swizzled global source
      const u16* ga = bf + (size_t)(i0 + r) * kD + k0 + ksl * 8;
      const u16* gb = bf + (size_t)(j0 + r) * kD + k0 + ksl * 8;
      GLOAD_LDS16(ga, Abuf + r * 64 + sl * 8);  // linear dest = tid*16B
      GLOAD_LDS16(gb, Bbuf + r * 64 + sl * 8);
    }
    __syncthreads();

#pragma unroll
    for (int k32 = 0; k32 < 2; ++k32) {
      bf16x8 a[4], bb[4];
#pragma unroll
      for (int mi = 0; mi < 4; ++mi) {
        const int ra   = wm * 64 + mi * 16 + llo;
        const int slot = (k32 * 4 + lhi) ^ (ra & 7);  // swizzled read
        a[mi] = *(const bf16x8*)(Abuf + ra * 64 + slot * 8);
      }
#pragma unroll
      for (int ni = 0; ni < 4; ++ni) {
        const int rb   = wn * 64 + ni * 16 + llo;
        const int slot = (k32 * 4 + lhi) ^ (rb & 7);
        bb[ni] = *(const bf16x8*)(Bbuf + rb * 64 + slot * 8);
      }
      __builtin_amdgcn_s_setprio(1);
#pragma unroll
      for (int mi = 0; mi < 4; ++mi)
#pragma unroll
        for (int ni = 0; ni < 4; ++ni)
          acc[mi][ni] = __builtin_amdgcn_mfma_f32_16x16x32_bf16(
              a[mi], bb[ni], acc[mi][ni], 0, 0, 0);
      __builtin_amdgcn_s_setprio(0);
    }
    __syncthreads();
  }

  // epilogue: t = (S - 1 + eq)^2 -> row sums always, col sums off-diagonal
  float rowacc[4][4] = {};
  float colacc[4] = {};
#pragma unroll
  for (int mi = 0; mi < 4; ++mi)
#pragma unroll
    for (int ni = 0; ni < 4; ++ni)
#pragma unroll
      for (int r = 0; r < 4; ++r) {
        // S-1 = (sq_i + sq_j)/D - 1 - (2/D)*gram
        float s1 = fmaf(acc[mi][ni][r], -kInv2D, sqi_s[mi][r] + sqjm1[ni]);
        s1 += (idi[mi][r] == idj[ni]) ? 1.0f : 0.0f;
        float t = s1 * s1;
        rowacc[mi][r] += t;
        colacc[ni] += t;
      }

  // row sums: reduce across the 16 llo lanes, atomic at llo==0
#pragma unroll
  for (int mi = 0; mi < 4; ++mi)
#pragma unroll
    for (int r = 0; r < 4; ++r) {
      float v = rowacc[mi][r];
      v += __shfl_xor(v, 1);
      v += __shfl_xor(v, 2);
      v += __shfl_xor(v, 4);
      v += __shfl_xor(v, 8);
      if (llo == 0)
        atomicAdd(&out[i0 + wm * 64 + mi * 16 + lhi * 4 + r], v * kInvN);
    }

  // col sums (off-diagonal tiles only): reduce across the 4 lhi groups
  if (!diag) {
#pragma unroll
    for (int ni = 0; ni < 4; ++ni) {
      float v = colacc[ni];
      v += __shfl_xor(v, 16);
      v += __shfl_xor(v, 32);
      if (lhi == 0)
        atomicAdd(&out[j0 + wn * 64 + ni * 16 + llo], v * kInvN);
    }
  }
}

// ---------------------------------------------------------------------------
extern "C" void kernel_launch(void* const* d_in, const int* in_sizes, int n_in,
                              void* d_out, int out_size, void* d_ws, size_t ws_size,
                              hipStream_t stream) {
  const float* samples = (const float*)d_in[0];
  const float* input1  = (const float*)d_in[1];
  float* out = (float*)d_out;

  char* ws = (char*)d_ws;
  u16*    bf   = (u16*)ws;                                  // 4 MB bf16 samples
  float2* sqid = (float2*)(ws + (size_t)4 * 1024 * 1024);   // 64 KB {sq, id}

  prep_kernel<<<kN / 4, 256, 0, stream>>>(samples, input1, bf, sqid, out);
  simloss_main<<<64 * 65 / 2, 256, 0, stream>>>(bf, sqid, out);
}

// Round 4
// 46.980 us; speedup vs baseline: 1.9187x; 1.5064x over previous
//
#include <hip/hip_runtime.h>

typedef unsigned short u16;
typedef __attribute__((ext_vector_type(8))) short bf16x8;  // 8 bf16 = 4 VGPRs (MFMA A/B frag)
typedef __attribute__((ext_vector_type(4))) float f32x4;   // MFMA C/D frag

constexpr int   kN    = 8192;
constexpr int   kD    = 256;
constexpr float kInvD = 1.0f / 256.0f;
constexpr float kInv2D = 2.0f / 256.0f;   // 2/D
constexpr float kInvN = 1.0f / 8192.0f;

#define GLOAD_LDS16(gptr, ldsptr)                                                   \
  __builtin_amdgcn_global_load_lds(                                                 \
      (const __attribute__((address_space(1))) unsigned int*)(gptr),                \
      (__attribute__((address_space(3))) unsigned int*)(ldsptr), 16, 0, 0)

// ---------------------------------------------------------------------------
// Kernel 1: prep — f32 -> bf16 convert, packed {sum-of-squares, id} per row,
// zero out. One wave per row (4 rows / 256-thread block).
// ---------------------------------------------------------------------------
__global__ __launch_bounds__(256) void prep_kernel(
    const float* __restrict__ samples, const float* __restrict__ input1,
    u16* __restrict__ bf, float2* __restrict__ sqid, float* __restrict__ out)
{
  const int row  = blockIdx.x * 4 + (threadIdx.x >> 6);
  const int lane = threadIdx.x & 63;

  const float4 v = *(const float4*)(samples + (size_t)row * kD + lane * 4);

  // bf16 convert, round-to-nearest-even
  float tmp[4] = {v.x, v.y, v.z, v.w};
  u16 h[4];
#pragma unroll
  for (int i = 0; i < 4; ++i) {
    union { float f; unsigned u; } c;
    c.f = tmp[i];
    unsigned r = c.u + 0x7fffu + ((c.u >> 16) & 1u);
    h[i] = (u16)(r >> 16);
  }
  *(ushort4*)(bf + (size_t)row * kD + lane * 4) = make_ushort4(h[0], h[1], h[2], h[3]);

  float ss = v.x * v.x + v.y * v.y + v.z * v.z + v.w * v.w;
#pragma unroll
  for (int m = 32; m >= 1; m >>= 1) ss += __shfl_xor(ss, m);

  if (lane == 0) {
    // ids[i] = input1[i, 0, F-1] -> flat index row*T*F + 7 (float-exact int)
    sqid[row] = make_float2(ss, input1[row * 32 + 7]);
    out[row]  = 0.0f;
  }
}

// ---------------------------------------------------------------------------
// Kernel 2: dense pass over the UPPER TRIANGLE of 128x128 tiles.
// t_ij = (S_ij - 1 + eq_ij)^2 == (S_ij - objid_dist)^2, id-compare folded
// into the epilogue. Off-diagonal tile (I,J): t feeds row sums (out[i]) AND
// col sums (out[j]); diagonal tiles row sums only. 2080 blocks; BK=64;
// 4 waves 2x2; mfma_f32_16x16x32_bf16 4x4/wave. global_load_lds (16B)
// staging, XOR-swizzled source + swizzled ds_read_b128 (rule #21).
// NOTE launch_bounds: (256,3) measured 108 VGPR / no spill (R2). (256,4)
// forced a 64+64 VGPR/AGPR split and spilled 100+ MB to scratch (R3) —
// acc[4][4] f32x4 is 64 regs by itself; do not cap below ~160.
// All sqid/id loads happen AFTER the K-loop to keep main-loop pressure low.
// ---------------------------------------------------------------------------
__global__ __launch_bounds__(256, 3) void simloss_main(
    const u16* __restrict__ bf, const float2* __restrict__ sqid,
    float* __restrict__ out)
{
  __shared__ u16 Abuf[128 * 64];  // 16 KB
  __shared__ u16 Bbuf[128 * 64];  // 16 KB

  const int tid  = threadIdx.x;
  const int lane = tid & 63;
  const int w    = tid >> 6;       // wave 0..3
  const int wm   = w >> 1;         // wave row (0..1)
  const int wn   = w & 1;          // wave col (0..1)
  const int llo  = lane & 15;
  const int lhi  = lane >> 4;

  // decode linear block id -> triangle tile (tj <= ti): rows I=tj, cols J=ti
  const int b = blockIdx.x;
  int ti = (int)((sqrtf(8.0f * (float)b + 1.0f) - 1.0f) * 0.5f);
  while ((ti + 1) * (ti + 2) / 2 <= b) ++ti;
  while (ti * (ti + 1) / 2 > b) --ti;
  const int tj = b - ti * (ti + 1) / 2;
  const int i0 = tj * 128;
  const int j0 = ti * 128;
  const bool diag = (ti == tj);

  const int sr = tid >> 3;  // staging row within 32-row chunk
  const int sl = tid & 7;   // staging 16B slot within 128B row

  f32x4 zero4 = {0.f, 0.f, 0.f, 0.f};
  f32x4 acc[4][4];
#pragma unroll
  for (int mi = 0; mi < 4; ++mi)
#pragma unroll
    for (int ni = 0; ni < 4; ++ni) acc[mi][ni] = zero4;

#pragma unroll
  for (int kt = 0; kt < 4; ++kt) {
    const int k0 = kt * 64;
    // stage A[128x64] and B[128x64] bf16 tiles: 4 calls x 16B/thread each
#pragma unroll
    for (int c = 0; c < 4; ++c) {
      const int r   = c * 32 + sr;
      const int ksl = sl ^ (r & 7);  // inverse-swizzled global source
      const u16* ga = bf + (size_t)(i0 + r) * kD + k0 + ksl * 8;
      const u16* gb = bf + (size_t)(j0 + r) * kD + k0 + ksl * 8;
      GLOAD_LDS16(ga, Abuf + r * 64 + sl * 8);  // linear dest = tid*16B
      GLOAD_LDS16(gb, Bbuf + r * 64 + sl * 8);
    }
    __syncthreads();

#pragma unroll
    for (int k32 = 0; k32 < 2; ++k32) {
      bf16x8 a[4], bb[4];
#pragma unroll
      for (int mi = 0; mi < 4; ++mi) {
        const int ra   = wm * 64 + mi * 16 + llo;
        const int slot = (k32 * 4 + lhi) ^ (ra & 7);  // swizzled read
        a[mi] = *(const bf16x8*)(Abuf + ra * 64 + slot * 8);
      }
#pragma unroll
      for (int ni = 0; ni < 4; ++ni) {
        const int rb   = wn * 64 + ni * 16 + llo;
        const int slot = (k32 * 4 + lhi) ^ (rb & 7);
        bb[ni] = *(const bf16x8*)(Bbuf + rb * 64 + slot * 8);
      }
      __builtin_amdgcn_s_setprio(1);
#pragma unroll
      for (int mi = 0; mi < 4; ++mi)
#pragma unroll
        for (int ni = 0; ni < 4; ++ni)
          acc[mi][ni] = __builtin_amdgcn_mfma_f32_16x16x32_bf16(
              a[mi], bb[ni], acc[mi][ni], 0, 0, 0);
      __builtin_amdgcn_s_setprio(0);
    }
    __syncthreads();
  }

  // ---- epilogue (loads deliberately AFTER the K-loop: short live range) ----
  float sqi_s[4][4], idi[4][4];
#pragma unroll
  for (int mi = 0; mi < 4; ++mi)
#pragma unroll
    for (int r = 0; r < 4; ++r) {
      const float2 p = sqid[i0 + wm * 64 + mi * 16 + lhi * 4 + r];
      sqi_s[mi][r] = p.x * kInvD;
      idi[mi][r]   = p.y;
    }

  float sqjm1[4], idj[4];
#pragma unroll
  for (int ni = 0; ni < 4; ++ni) {
    const float2 p = sqid[j0 + wn * 64 + ni * 16 + llo];
    sqjm1[ni] = p.x * kInvD - 1.0f;
    idj[ni]   = p.y;
  }

  // t = (S - 1 + eq)^2 -> row sums always, col sums off-diagonal
  float rowacc[4][4] = {};
  float colacc[4] = {};
#pragma unroll
  for (int mi = 0; mi < 4; ++mi)
#pragma unroll
    for (int ni = 0; ni < 4; ++ni)
#pragma unroll
      for (int r = 0; r < 4; ++r) {
        // S-1 = (sq_i + sq_j)/D - 1 - (2/D)*gram
        float s1 = fmaf(acc[mi][ni][r], -kInv2D, sqi_s[mi][r] + sqjm1[ni]);
        s1 += (idi[mi][r] == idj[ni]) ? 1.0f : 0.0f;
        float t = s1 * s1;
        rowacc[mi][r] += t;
        colacc[ni] += t;
      }

  // row sums: reduce across the 16 llo lanes, atomic at llo==0
#pragma unroll
  for (int mi = 0; mi < 4; ++mi)
#pragma unroll
    for (int r = 0; r < 4; ++r) {
      float v = rowacc[mi][r];
      v += __shfl_xor(v, 1);
      v += __shfl_xor(v, 2);
      v += __shfl_xor(v, 4);
      v += __shfl_xor(v, 8);
      if (llo == 0)
        atomicAdd(&out[i0 + wm * 64 + mi * 16 + lhi * 4 + r], v * kInvN);
    }

  // col sums (off-diagonal tiles only): reduce across the 4 lhi groups
  if (!diag) {
#pragma unroll
    for (int ni = 0; ni < 4; ++ni) {
      float v = colacc[ni];
      v += __shfl_xor(v, 16);
      v += __shfl_xor(v, 32);
      if (lhi == 0)
        atomicAdd(&out[j0 + wn * 64 + ni * 16 + llo], v * kInvN);
    }
  }
}

// ---------------------------------------------------------------------------
extern "C" void kernel_launch(void* const* d_in, const int* in_sizes, int n_in,
                              void* d_out, int out_size, void* d_ws, size_t ws_size,
                              hipStream_t stream) {
  const float* samples = (const float*)d_in[0];
  const float* input1  = (const float*)d_in[1];
  float* out = (float*)d_out;

  char* ws = (char*)d_ws;
  u16*    bf   = (u16*)ws;                                  // 4 MB bf16 samples
  float2* sqid = (float2*)(ws + (size_t)4 * 1024 * 1024);   // 64 KB {sq, id}

  prep_kernel<<<kN / 4, 256, 0, stream>>>(samples, input1, bf, sqid, out);
  simloss_main<<<64 * 65 / 2, 256, 0, stream>>>(bf, sqid, out);
}